// Round 6
// baseline (307.552 us; speedup 1.0000x reference)
//
#include <hip/hip_runtime.h>
#include <hip/hip_bf16.h>
#include <cstdint>

// SpatialAttentionModule: x[4,256,64,64] fp32; q=Wq x, k=Wk x, v=Wv x (1x1 conv);
// energy = q^T k per batch (N=4096), softmax over j, out = gamma*(v@attn^T) + x.
//
// Round-6: occupancy attack. R2-R5 all ran 1 block/CU = 1 wave/SIMD and all
// land ~180us with ~55% pure stall (MfmaUtil 15 + VALUBusy 30, all throughput
// ceilings far away). R6: Q=32 per block -> grid 512 = 2 blocks/CU,
// JT=32 -> LDS ~68 KB (2 fit in 160), VGPR ~160 (<256) -> 2 waves/SIMD.
// Co-resident block hides the other's barrier/DMA/dependency stalls.
// Splits (no redundant LDS reads): S: wave (kg=w&1) keys kg*16..+16 x
// (qg=w>>1) queries qg*16..+16. PV: wave owns channels w*64..+64 x all 32 q.
// Cross-wave softmax exchange via tiny LDS buffer (max + end-of-kernel l).
// fp16 everywhere (R4 absmax 0.031, 3.3x margin).
// MFMA layouts (HW-verified, learn_hip m89/m91, dtype-independent):
//   A[m=lane&15][k=quad*8+j], B[k=quad*8+j][n=lane&15], C/D: col=lane&15, row=quad*4+reg.

#define C_DIM 256
#define N_DIM 4096
#define B_DIM 4

typedef _Float16 f16;
typedef f16 f16x8 __attribute__((ext_vector_type(8)));
typedef f16 f16x4 __attribute__((ext_vector_type(4)));
typedef float f32x4 __attribute__((ext_vector_type(4)));

__device__ __forceinline__ void dma16(const f16* g, f16* l) {
  __builtin_amdgcn_global_load_lds(
      (const __attribute__((address_space(1))) unsigned int*)g,
      (__attribute__((address_space(3))) unsigned int*)l, 16, 0, 0);
}

// ---------------- prep: transpose-cast x -> xs fp16 [B*N][256] ----------------
__global__ __launch_bounds__(256) void k_prep_xs(const float* __restrict__ x,
                                                 f16* __restrict__ xs) {
  __shared__ float tile[64][65];
  const int b = blockIdx.z, nb = blockIdx.x * 64, cb = blockIdx.y * 64;
  const float* xb = x + (size_t)b * C_DIM * N_DIM;
  for (int i = threadIdx.x; i < 64 * 64; i += 256) {
    int c = i >> 6, n = i & 63;
    tile[c][n] = xb[(size_t)(cb + c) * N_DIM + nb + n];
  }
  __syncthreads();
  f16* xsb = xs + (size_t)b * N_DIM * C_DIM;
  for (int i = threadIdx.x; i < 64 * 64; i += 256) {
    int n = i >> 6, c = i & 63;
    xsb[(size_t)(nb + n) * C_DIM + cb + c] = (f16)tile[c][n];
  }
}

// ---------------- prep: cast 3 weight matrices -> fp16 [3*256][256] ----------------
__global__ __launch_bounds__(256) void k_cast_w(const float* __restrict__ Wq,
                                                const float* __restrict__ Wk,
                                                const float* __restrict__ Wv,
                                                f16* __restrict__ Wh) {
  int i = blockIdx.x * 256 + threadIdx.x;
  int sel = i >> 16, j = i & 65535;
  const float* s = (sel == 0) ? Wq : (sel == 1) ? Wk : Wv;
  Wh[i] = (f16)s[j];
}

// ---------------- QKV projection GEMMs (fp16, K=256) ----------------
__global__ __launch_bounds__(256) void k_proj(const f16* __restrict__ xs,
                                              const f16* __restrict__ Wh,
                                              const float* __restrict__ bq,
                                              const float* __restrict__ bk,
                                              const float* __restrict__ bv,
                                              f16* __restrict__ Qh,
                                              f16* __restrict__ Kh,
                                              f16* __restrict__ Vh) {
  const int z = blockIdx.y;
  const int w = threadIdx.x >> 6, lane = threadIdx.x & 63;
  const int quad = lane >> 4, li = lane & 15;
  const f16* W = Wh + (size_t)z * 65536;
  const float* bias = (z == 0) ? bq : (z == 1) ? bk : bv;

  if (z < 2) {
    f16* out = (z == 0) ? Qh : Kh;
    const int g0 = (blockIdx.x * 4 + w) * 16;
    f16x8 a[8];
    const f16* arow = xs + (size_t)(g0 + li) * C_DIM + quad * 8;
#pragma unroll
    for (int kf = 0; kf < 8; kf++) a[kf] = *(const f16x8*)(arow + kf * 32);
    for (int ot = 0; ot < 16; ot++) {
      f32x4 acc = {0.f, 0.f, 0.f, 0.f};
      const f16* brow = W + (size_t)(ot * 16 + li) * C_DIM + quad * 8;
#pragma unroll
      for (int kf = 0; kf < 8; kf++) {
        f16x8 bf = *(const f16x8*)(brow + kf * 32);
        acc = __builtin_amdgcn_mfma_f32_16x16x32_f16(a[kf], bf, acc, 0, 0, 0);
      }
      float bb = bias[ot * 16 + li];
      f16* orow = out + (size_t)g0 * C_DIM + ot * 16 + li;
#pragma unroll
      for (int r = 0; r < 4; r++)
        orow[(size_t)(quad * 4 + r) * C_DIM] = (f16)(acc[r] + bb);
    }
  } else {
    const int t = blockIdx.x * 4 + w;
    const int b = t >> 8, j0 = (t & 255) * 16;
    f16x8 bfr[8];
    const f16* brow = xs + (size_t)(b * N_DIM + j0 + li) * C_DIM + quad * 8;
#pragma unroll
    for (int kf = 0; kf < 8; kf++) bfr[kf] = *(const f16x8*)(brow + kf * 32);
    for (int ot = 0; ot < 16; ot++) {
      f32x4 acc = {0.f, 0.f, 0.f, 0.f};
      const f16* arow = W + (size_t)(ot * 16 + li) * C_DIM + quad * 8;
#pragma unroll
      for (int kf = 0; kf < 8; kf++) {
        f16x8 af = *(const f16x8*)(arow + kf * 32);
        acc = __builtin_amdgcn_mfma_f32_16x16x32_f16(af, bfr[kf], acc, 0, 0, 0);
      }
      f16* obase = Vh + ((size_t)(b * C_DIM + ot * 16 + quad * 4)) * N_DIM + j0 + li;
#pragma unroll
      for (int r = 0; r < 4; r++) {
        float bb = bias[ot * 16 + quad * 4 + r];
        obase[(size_t)r * N_DIM] = (f16)(acc[r] + bb);
      }
    }
  }
}

// ---------------- fused attention ----------------
// grid (128,4): 32-query block, batch; 4 waves; 2 blocks/CU.
// Tile = 32 keys, NT=128. DMA dbuf staging (8 dma16/wave/tile).
// LDS (f16 units):
//   K: phys(r,k) = (r>>1)*528 + (r&1)*256 + k     (16 pairs/buf, DMA span 1KB)
//   V: phys(c,j) = (c>>4)*520 + (c&15)*32 + j     (16 groups/buf, DMA span 1KB)
//   P: [32 q][PSTR=40]
//   mx: float[32][2] exchange (max during loop, l at end)
#define Q_BLK 32
#define JT 32
#define NT (N_DIM / JT)
#define K0_OFF 0
#define K1_OFF 8448
#define V0_OFF 16896
#define V1_OFF 25216
#define P_OFF  33536
#define MX_OFF 34816
#define PSTR 40
#define SMEM_F16 34944        // 69,888 B -> 2 blocks/CU

__global__ __launch_bounds__(256, 2) void k_attn(const f16* __restrict__ Qh,
                                                 const f16* __restrict__ Kh,
                                                 const f16* __restrict__ Vh,
                                                 const float* __restrict__ x,
                                                 const float* __restrict__ gamma_p,
                                                 float* __restrict__ out) {
  __shared__ __align__(16) f16 smem[SMEM_F16];
  const int b = blockIdx.y;
  const int tid = threadIdx.x;
  const int w = tid >> 6, lane = tid & 63;
  const int quad = lane >> 4, li = lane & 15;
  const int q0 = blockIdx.x * Q_BLK;
  const int qg = w >> 1;     // S role: query group (0/1)
  const int kg = w & 1;      // S role: key half (0/1)
  float* mx = (float*)(smem + MX_OFF);
  f16* Pq = smem + P_OFF;

  // Q frags: wave's 16 queries (B-operand: n=q, k=channel)
  f16x8 qf[8];
  {
    const f16* qrow = Qh + (size_t)(b * N_DIM + q0 + qg * 16 + li) * C_DIM + quad * 8;
#pragma unroll
    for (int kf = 0; kf < 8; kf++) qf[kf] = *(const f16x8*)(qrow + kf * 32);
  }
  const f16* Kb = Kh + (size_t)b * N_DIM * C_DIM;
  const f16* Vb = Vh + (size_t)b * C_DIM * N_DIM;

  // DMA addressing (strength-reduced): K global is contiguous per tile:
  //   src = Kb + t*JT*C_DIM + p*512 + lane*8, dst = Kbuf + p*528 + lane*8, p=w*4+i
  // V: src = Vb + t*JT + (g*16 + (lane>>2))*N_DIM + (lane&3)*8, dst = Vbuf + g*520 + lane*8
  const int kland = lane * 8;
  const size_t vland = (size_t)(lane >> 2) * N_DIM + (lane & 3) * 8;

  const float LOG2E = 1.4426950408889634f;
  float m[2] = {-3.0e38f, -3.0e38f};
  float l_lane = 0.0f;
  f32x4 acc[4][2];   // [ct: 16-ch block][cb: q group]
#pragma unroll
  for (int a = 0; a < 4; a++)
#pragma unroll
    for (int c = 0; c < 2; c++) acc[a][c] = (f32x4){0.f, 0.f, 0.f, 0.f};

  // prologue: DMA tile 0 -> buf0
#pragma unroll
  for (int i = 0; i < 4; i++) {
    int p = w * 4 + i;
    dma16(Kb + p * 512 + kland, smem + K0_OFF + p * 528 + kland);
    dma16(Vb + (size_t)(p * 16) * N_DIM + vland, smem + V0_OFF + p * 520 + kland);
  }
  __syncthreads();

  for (int t = 0; t < NT; t++) {
    const f16* Kc = smem + ((t & 1) ? K1_OFF : K0_OFF);
    const f16* Vc = smem + ((t & 1) ? V1_OFF : V0_OFF);

    // ---- S: wave's 16 keys x 16 queries (K=256) ----
    f32x4 s = {0.f, 0.f, 0.f, 0.f};
    {
      const int r = kg * 16 + li;
      const f16* krow = Kc + (r >> 1) * 528 + (r & 1) * 256 + quad * 8;
#pragma unroll
      for (int kf = 0; kf < 8; kf++) {
        f16x8 kfr = *(const f16x8*)(krow + kf * 32);
        s = __builtin_amdgcn_mfma_f32_16x16x32_f16(kfr, qf[kf], s, 0, 0, 0);
      }
    }

    // partial max over wave's 16 keys, per query q = qg*16+li
    float pm = fmaxf(fmaxf(s[0], s[1]), fmaxf(s[2], s[3]));
    pm = fmaxf(pm, __shfl_xor(pm, 16));
    pm = fmaxf(pm, __shfl_xor(pm, 32));
    if (lane < 16) mx[(qg * 16 + lane) * 2 + kg] = pm;
    __syncthreads();                     // barrier A: mx visible; buf[t-1] free

    // DMA tile t+1 into the other buffer
    if (t + 1 < NT) {
      f16* Kn = smem + ((t & 1) ? K0_OFF : K1_OFF);
      f16* Vn = smem + ((t & 1) ? V0_OFF : V1_OFF);
      const f16* kg_p = Kb + (size_t)(t + 1) * (JT * C_DIM);
      const f16* vg_p = Vb + (t + 1) * JT;
#pragma unroll
      for (int i = 0; i < 4; i++) {
        int p = w * 4 + i;
        dma16(kg_p + p * 512 + kland, Kn + p * 528 + kland);
        dma16(vg_p + (size_t)(p * 16) * N_DIM + vland, Vn + p * 520 + kland);
      }
    }

    // block max per query group, alpha, rescale
    float al[2];
    bool need = false;
#pragma unroll
    for (int cb = 0; cb < 2; cb++) {
      float2 mm = *(const float2*)&mx[(cb * 16 + li) * 2];
      float bm = fmaxf(mm.x, mm.y);
      float nm = fmaxf(m[cb], bm);
      al[cb] = __expf(m[cb] - nm);
      need |= (nm > m[cb]);
      m[cb] = nm;
    }
    if (__any(need)) {
      l_lane *= al[qg];
#pragma unroll
      for (int ct = 0; ct < 4; ct++) {
#pragma unroll
        for (int cb = 0; cb < 2; cb++) acc[ct][cb] *= al[cb];
      }
    }

    // p = exp(s - m), P write (C-layout row j = kg*16+quad*4+r, col q = qg*16+li)
    {
      float p0 = __expf(s[0] - m[qg]);
      float p1 = __expf(s[1] - m[qg]);
      float p2 = __expf(s[2] - m[qg]);
      float p3 = __expf(s[3] - m[qg]);
      l_lane += (p0 + p1) + (p2 + p3);
      *(f16x4*)(Pq + (qg * 16 + li) * PSTR + kg * 16 + quad * 4) =
          (f16x4){(f16)p0, (f16)p1, (f16)p2, (f16)p3};
    }
    __syncthreads();                     // barrier B: P visible; DMA drained

    // ---- PV: wave's 64 channels x 32 queries over 32 keys (K=32) ----
    f16x8 pf[2];
#pragma unroll
    for (int cb = 0; cb < 2; cb++)
      pf[cb] = *(const f16x8*)(Pq + (cb * 16 + li) * PSTR + quad * 8);
#pragma unroll
    for (int ct = 0; ct < 4; ct++) {
      f16x8 vf = *(const f16x8*)(Vc + (w * 4 + ct) * 520 + li * 32 + quad * 8);
#pragma unroll
      for (int cb = 0; cb < 2; cb++)
        acc[ct][cb] = __builtin_amdgcn_mfma_f32_16x16x32_f16(vf, pf[cb], acc[ct][cb], 0, 0, 0);
    }
    // next iteration's barrier A protects mx/P reuse
  }

  // ---- epilogue: merge l across key-halves, scale, store ----
  l_lane += __shfl_xor(l_lane, 16);
  l_lane += __shfl_xor(l_lane, 32);
  __syncthreads();
  if (lane < 16) mx[(qg * 16 + lane) * 2 + kg] = l_lane;
  __syncthreads();
  const float g = gamma_p[0];
  float scale[2];
#pragma unroll
  for (int cb = 0; cb < 2; cb++) {
    float2 ll = *(const float2*)&mx[(cb * 16 + li) * 2];
    scale[cb] = g / (ll.x + ll.y);
  }

  const float* xb = x + (size_t)b * C_DIM * N_DIM;
  float* ob = out + (size_t)b * C_DIM * N_DIM;
#pragma unroll
  for (int ct = 0; ct < 4; ct++) {
#pragma unroll
    for (int r = 0; r < 4; r++) {
      int ch = w * 64 + ct * 16 + quad * 4 + r;
#pragma unroll
      for (int cb = 0; cb < 2; cb++) {
        size_t off = (size_t)ch * N_DIM + q0 + cb * 16 + li;
        ob[off] = acc[ct][cb][r] * scale[cb] + xb[off];
      }
    }
  }
}

extern "C" void kernel_launch(void* const* d_in, const int* in_sizes, int n_in,
                              void* d_out, int out_size, void* d_ws, size_t ws_size,
                              hipStream_t stream) {
  const float* x     = (const float*)d_in[0];
  const float* Wq    = (const float*)d_in[1];
  const float* bq    = (const float*)d_in[2];
  const float* Wk    = (const float*)d_in[3];
  const float* bk    = (const float*)d_in[4];
  const float* Wv    = (const float*)d_in[5];
  const float* bv    = (const float*)d_in[6];
  const float* gamma = (const float*)d_in[7];
  float* out = (float*)d_out;

  // workspace: xs 8MB | Qh 8MB | Kh 8MB | Vh 8MB | Wh 384KB  (~32.4 MB)
  char* ws = (char*)d_ws;
  f16* xs = (f16*)(ws);
  f16* Qh = (f16*)(ws + (size_t)8  * 1024 * 1024);
  f16* Kh = (f16*)(ws + (size_t)16 * 1024 * 1024);
  f16* Vh = (f16*)(ws + (size_t)24 * 1024 * 1024);
  f16* Wh = (f16*)(ws + (size_t)32 * 1024 * 1024);

  k_prep_xs<<<dim3(64, 4, 4), 256, 0, stream>>>(x, xs);
  k_cast_w<<<dim3(768), 256, 0, stream>>>(Wq, Wk, Wv, Wh);
  k_proj<<<dim3(256, 3), 256, 0, stream>>>(xs, Wh, bq, bk, bv, Qh, Kh, Vh);
  k_attn<<<dim3(128, 4), 256, 0, stream>>>(Qh, Kh, Vh, x, gamma, out);
}